// Round 7
// baseline (2090.305 us; speedup 1.0000x reference)
//
#include <hip/hip_runtime.h>
#include <hip/hip_bf16.h>
#include <stdint.h>

#define RANK 32
#define SCALE (1.0f / 32.0f)

typedef __bf16 bf16x8 __attribute__((ext_vector_type(8)));
typedef float f32x4 __attribute__((ext_vector_type(4)));

// ---------------------------------------------------------------------------
// async global->LDS, 16B per lane
// ---------------------------------------------------------------------------
__device__ __forceinline__ void gload16(const void* g, void* l) {
  __builtin_amdgcn_global_load_lds(
      (const __attribute__((address_space(1))) unsigned int*)g,
      (__attribute__((address_space(3))) unsigned int*)l, 16, 0, 0);
}

__device__ __forceinline__ unsigned short f2bf(float f) {
  __hip_bfloat16 h = __float2bfloat16(f);
  return *reinterpret_cast<unsigned short*>(&h);
}

// ---------------------------------------------------------------------------
// Bt[o][r] = B[r][o]
// ---------------------------------------------------------------------------
__global__ __launch_bounds__(256) void transpose_B_k(const float* __restrict__ B,
                                                     float* __restrict__ Bt,
                                                     int Dout) {
  int idx = blockIdx.x * 256 + threadIdx.x;
  int r = idx / Dout;
  int o = idx - r * Dout;
  Bt[(long long)o * RANK + r] = B[idx];
}

// ---------------------------------------------------------------------------
// W'b[o][i] = bf16( W[o][i] + SCALE * dot32(A[i][:], Bt[o][:]) )
// ---------------------------------------------------------------------------
__global__ __launch_bounds__(256) void merge_W_k(const float* __restrict__ W,
                                                 const float* __restrict__ A,
                                                 const float* __restrict__ Bt,
                                                 unsigned short* __restrict__ Wb,
                                                 int Din, int Dout) {
  __shared__ float sB[16 * RANK];
  int nib = Din / 256;
  int ib = blockIdx.x % nib;
  int ob = blockIdx.x / nib;
  int i0 = ib * 256, o0 = ob * 16;
  int t = threadIdx.x;

  if (t < 128) {
    reinterpret_cast<float4*>(sB)[t] =
        reinterpret_cast<const float4*>(Bt + (long long)o0 * RANK)[t];
  }

  float a[RANK];
  const float4* Ap = reinterpret_cast<const float4*>(A + (long long)(i0 + t) * RANK);
#pragma unroll
  for (int c = 0; c < RANK / 4; ++c) {
    float4 v = Ap[c];
    a[c * 4 + 0] = v.x; a[c * 4 + 1] = v.y;
    a[c * 4 + 2] = v.z; a[c * 4 + 3] = v.w;
  }
  __syncthreads();

  for (int o = 0; o < 16; ++o) {
    float d = 0.f;
#pragma unroll
    for (int j = 0; j < RANK; ++j) d += a[j] * sB[o * RANK + j];
    long long off = (long long)(o0 + o) * Din + i0 + t;
    float w = __builtin_nontemporal_load(&W[off]);
    Wb[off] = f2bf(w + SCALE * d);
  }
}

// ---------------------------------------------------------------------------
// x fp32 -> bf16, 8 elems/thread (nt loads via native ext_vector)
// ---------------------------------------------------------------------------
__global__ __launch_bounds__(256) void cast_x_k(const float* __restrict__ in,
                                                unsigned short* __restrict__ out,
                                                long long n8) {
  long long i = (long long)blockIdx.x * 256 + threadIdx.x;
  if (i >= n8) return;
  const f32x4* in4 = reinterpret_cast<const f32x4*>(in) + i * 2;
  f32x4 v0 = __builtin_nontemporal_load(in4);
  f32x4 v1 = __builtin_nontemporal_load(in4 + 1);
  union { unsigned short u[8]; uint4 q; } p;
  p.u[0] = f2bf(v0.x); p.u[1] = f2bf(v0.y); p.u[2] = f2bf(v0.z); p.u[3] = f2bf(v0.w);
  p.u[4] = f2bf(v1.x); p.u[5] = f2bf(v1.y); p.u[6] = f2bf(v1.z); p.u[7] = f2bf(v1.w);
  reinterpret_cast<uint4*>(out)[i] = p.q;
}

// ---------------------------------------------------------------------------
// R7: 256x256 / BK=32 / 8 waves (2Mx4N) / 2 phases per K-tile / 64 KiB LDS
// => 2 blocks/CU co-resident (4 waves/SIMD): block A's barrier/vmcnt stalls
// are covered by block B's MFMAs (m114/m97 mechanism).
//
// Units (1 gload-issue each, 128 rows x 32 k): Ra1=A[0:128] Ra2=A[128:256]
// Rb1=B[0:128] Rb2=B[128:256]. Tile X lives in buf[X&1].
// Read map: P1 reads Ra1,Rb1,Rb2 (a_lo + all b); P2 reads Ra2 (a_hi).
// Stage map: P1(X) stages Ra2(X+1)->buf^1  [region sealed at P2(X-1) close]
//            P2(X) stages Ra1,Rb1,Rb2(X+2)->buf [sealed at P1(X) close]
// Gates (in-order vmcnt; count = units issued AFTER the needed ones):
//   P1(X): needs lo(X) [P2(X-2)]; newer = Ra2(X)+lo(X+1)+Ra2(X+1) = 5
//          -> vmcnt(5) for X<=NT-2, vmcnt(1) at X=NT-1
//   P2(X): needs Ra2(X) [P1(X-1)]; newer = lo(X+1)+Ra2(X+1)+lo(X+2) = 7
//          -> vmcnt(7) X<=NT-3, vmcnt(4) X=NT-2, vmcnt(0) X=NT-1
// Prologue: tile0 (4U oldest) + lo(1) (3U); vmcnt(3) drains tile0 exactly.
// Swizzle (64-B rows = 4x16B chunks): chunk ^= (row ^ row>>2) & 3 on BOTH
// sides (inverse-swizzled global source + swizzled ds_read) -> quarter-wave
// reads are 2-way bank aliased max (free, m136).
// ---------------------------------------------------------------------------
__device__ __forceinline__ void stage1(const unsigned short* g, int K, int koff,
                                       int row0, unsigned short* ldsbase,
                                       int t, int wid) {
  int r = t >> 2;                               // 0..127 local row
  int cg = (t & 3) ^ ((r ^ (r >> 2)) & 3);      // inverse-swizzled 16B chunk
  gload16(g + (long long)(row0 + r) * K + koff + cg * 8,
          ldsbase + row0 * 32 + wid * 512);
}

__device__ __forceinline__ int swz_off32(int rowl, int k) {
  return rowl * 32 + ((((k) >> 3) ^ ((rowl ^ (rowl >> 2)) & 3)) << 3);
}

__global__ __launch_bounds__(512, 4) void gemm256_bias_k(
    const unsigned short* __restrict__ Xb,   // [M][K] bf16
    const unsigned short* __restrict__ Wb,   // [N][K] bf16
    const float* __restrict__ bias,          // [N]
    float* __restrict__ Out,                 // [M][N] fp32
    int M, int N, int K) {
  __shared__ unsigned short As[2][256 * 32];
  __shared__ unsigned short Bs[2][256 * 32];   // 64 KiB total

  int nbn = N / 256;
  int cpx = gridDim.x >> 3;
  int bid = blockIdx.x;
  int xcd = bid & 7, local = bid >> 3;
  int bm, bn;
  int mrows = cpx / nbn;
  if (mrows * nbn == cpx) {
    bn = local / mrows;
    bm = xcd * mrows + (local - bn * mrows);   // bm-fastest: B-panel L2-hot
  } else {
    int swz = xcd * cpx + local;
    bm = swz / nbn; bn = swz % nbn;
  }

  int t = threadIdx.x;
  int wid = t >> 6, lane = t & 63;
  int wr = wid >> 2, wc = wid & 3;             // 2x4 wave grid
  int lr = lane & 15, kq = (lane >> 4) * 8;
  int wr64 = wr * 64, wc32 = wc * 32;

  const unsigned short* ga = Xb + (long long)bm * 256 * K;
  const unsigned short* gb = Wb + (long long)bn * 256 * K;

  f32x4 acc[8][4] = {};
  bf16x8 a[4], b[4];

  const int NT = K / 32;        // 128

#define LDA(BUF, ROWBASE) \
  (*(const bf16x8*)&As[BUF][swz_off32((ROWBASE) + lr, kq)])
#define LDB(BUF, ROWBASE) \
  (*(const bf16x8*)&Bs[BUF][swz_off32((ROWBASE) + lr, kq)])

  // ---- prologue: tile0 full (oldest 4) + lo(1); drain tile0 via vmcnt(3)
  stage1(ga, K, 0, 0,    &As[0][0], t, wid);   // Ra1(0)
  stage1(gb, K, 0, 0,    &Bs[0][0], t, wid);   // Rb1(0)
  stage1(gb, K, 0, 128,  &Bs[0][0], t, wid);   // Rb2(0)
  stage1(ga, K, 0, 128,  &As[0][0], t, wid);   // Ra2(0)
  stage1(ga, K, 32, 0,   &As[1][0], t, wid);   // Ra1(1)
  stage1(gb, K, 32, 0,   &Bs[1][0], t, wid);   // Rb1(1)
  stage1(gb, K, 32, 128, &Bs[1][0], t, wid);   // Rb2(1)
  asm volatile("s_waitcnt vmcnt(3)" ::: "memory");
  __builtin_amdgcn_s_barrier();

  for (int X = 0; X < NT; ++X) {
    const int cur = X & 1;

    // ---------- P1: read a_lo + all b; stage Ra2(X+1); gate; MFMA lo-half
#pragma unroll
    for (int m = 0; m < 4; ++m) a[m] = LDA(cur, wr64 + m * 16);
    b[0] = LDB(cur, wc32);
    b[1] = LDB(cur, wc32 + 16);
    b[2] = LDB(cur, 128 + wc32);
    b[3] = LDB(cur, 128 + wc32 + 16);
    if (X + 1 < NT) stage1(ga, K, (X + 1) * 32, 128, &As[cur ^ 1][0], t, wid);
    if (X <= NT - 2) { asm volatile("s_waitcnt vmcnt(5)" ::: "memory"); }
    else             { asm volatile("s_waitcnt vmcnt(1)" ::: "memory"); }
    __builtin_amdgcn_s_barrier();
    __builtin_amdgcn_s_setprio(1);
#pragma unroll
    for (int m = 0; m < 4; ++m)
#pragma unroll
      for (int n = 0; n < 4; ++n)
        acc[m][n] = __builtin_amdgcn_mfma_f32_16x16x32_bf16(a[m], b[n], acc[m][n], 0, 0, 0);
    __builtin_amdgcn_s_setprio(0);
    __builtin_amdgcn_s_barrier();

    // ---------- P2: read a_hi; stage Ra1/Rb1/Rb2(X+2); gate; MFMA hi-half
#pragma unroll
    for (int m = 0; m < 4; ++m) a[m] = LDA(cur, 128 + wr64 + m * 16);
    if (X + 2 < NT) {
      stage1(ga, K, (X + 2) * 32, 0,   &As[cur][0], t, wid);
      stage1(gb, K, (X + 2) * 32, 0,   &Bs[cur][0], t, wid);
      stage1(gb, K, (X + 2) * 32, 128, &Bs[cur][0], t, wid);
    }
    if (X <= NT - 3)      { asm volatile("s_waitcnt vmcnt(7)" ::: "memory"); }
    else if (X == NT - 2) { asm volatile("s_waitcnt vmcnt(4)" ::: "memory"); }
    else                  { asm volatile("s_waitcnt vmcnt(0)" ::: "memory"); }
    __builtin_amdgcn_s_barrier();
    __builtin_amdgcn_s_setprio(1);
#pragma unroll
    for (int m = 0; m < 4; ++m)
#pragma unroll
      for (int n = 0; n < 4; ++n)
        acc[4 + m][n] = __builtin_amdgcn_mfma_f32_16x16x32_bf16(a[m], b[n], acc[4 + m][n], 0, 0, 0);
    __builtin_amdgcn_s_setprio(0);
    __builtin_amdgcn_s_barrier();
  }
#undef LDA
#undef LDB

  // epilogue (identical mapping to R4/R6, nt stores):
  // rows: m<4 -> wr64 + m*16 ; m>=4 -> 128 + wr64 + (m-4)*16
  // cols: n<2 -> wc32 + n*16 ; n>=2 -> 128 + wc32 + (n-2)*16
  int rq = (lane >> 4) * 4;
#pragma unroll
  for (int n = 0; n < 4; ++n) {
    int gc = bn * 256 + (n >= 2 ? 128 : 0) + wc32 + (n & 1) * 16 + lr;
    float bv = bias[gc];
#pragma unroll
    for (int m = 0; m < 8; ++m) {
      long long gr = (long long)bm * 256 + (m >= 4 ? 128 : 0) + wr64 + (m & 3) * 16 + rq;
#pragma unroll
      for (int v = 0; v < 4; ++v)
        __builtin_nontemporal_store(acc[m][n][v] + bv, &Out[(gr + v) * N + gc]);
    }
  }
}

// ---------------------------------------------------------------------------
extern "C" void kernel_launch(void* const* d_in, const int* in_sizes, int n_in,
                              void* d_out, int out_size, void* d_ws, size_t ws_size,
                              hipStream_t stream) {
  const float* x    = (const float*)d_in[0];
  const float* W    = (const float*)d_in[1];
  const float* bias = (const float*)d_in[2];
  const float* A    = (const float*)d_in[3];
  const float* B    = (const float*)d_in[4];

  int Din  = in_sizes[3] / RANK;                 // 4096
  int Dout = in_sizes[4] / RANK;                 // 4096
  long long M = (long long)in_sizes[0] / Din;    // 8192

  size_t xb_bytes = (size_t)M * Din * 2;
  size_t wb_bytes = (size_t)Dout * Din * 2;
  size_t bt_bytes = (size_t)Dout * RANK * 4;
  if (ws_size < xb_bytes + wb_bytes + bt_bytes) return;

  char* ws = (char*)d_ws;
  unsigned short* Xb = (unsigned short*)ws;
  unsigned short* Wb = (unsigned short*)(ws + xb_bytes);
  float* Bt          = (float*)(ws + xb_bytes + wb_bytes);

  transpose_B_k<<<dim3((Dout * RANK) / 256), dim3(256), 0, stream>>>(B, Bt, Dout);
  merge_W_k<<<dim3((Dout / 16) * (Din / 256)), dim3(256), 0, stream>>>(W, A, Bt, Wb, Din, Dout);
  long long n8 = M * Din / 8;
  cast_x_k<<<dim3((unsigned)(n8 / 256)), dim3(256), 0, stream>>>(x, Xb, n8);
  gemm256_bias_k<<<dim3((unsigned)((M / 256) * (Dout / 256))), dim3(512), 0, stream>>>(
      Xb, Wb, bias, (float*)d_out, (int)M, Dout, Din);
}

// Round 9
// 345.772 us; speedup vs baseline: 6.0453x; 6.0453x over previous
//
#include <hip/hip_runtime.h>
#include <hip/hip_bf16.h>
#include <stdint.h>

#define RANK 32
#define SCALE (1.0f / 32.0f)

typedef __bf16 bf16x8 __attribute__((ext_vector_type(8)));
typedef float f32x4 __attribute__((ext_vector_type(4)));

// ---------------------------------------------------------------------------
// async global->LDS, 16B per lane
// ---------------------------------------------------------------------------
__device__ __forceinline__ void gload16(const void* g, void* l) {
  __builtin_amdgcn_global_load_lds(
      (const __attribute__((address_space(1))) unsigned int*)g,
      (__attribute__((address_space(3))) unsigned int*)l, 16, 0, 0);
}

__device__ __forceinline__ unsigned short f2bf(float f) {
  __hip_bfloat16 h = __float2bfloat16(f);
  return *reinterpret_cast<unsigned short*>(&h);
}

// ---------------------------------------------------------------------------
// Bt[o][r] = B[r][o]
// ---------------------------------------------------------------------------
__global__ __launch_bounds__(256) void transpose_B_k(const float* __restrict__ B,
                                                     float* __restrict__ Bt,
                                                     int Dout) {
  int idx = blockIdx.x * 256 + threadIdx.x;
  int r = idx / Dout;
  int o = idx - r * Dout;
  Bt[(long long)o * RANK + r] = B[idx];
}

// ---------------------------------------------------------------------------
// W'b[o][i] = bf16( W[o][i] + SCALE * dot32(A[i][:], Bt[o][:]) )
// ---------------------------------------------------------------------------
__global__ __launch_bounds__(256) void merge_W_k(const float* __restrict__ W,
                                                 const float* __restrict__ A,
                                                 const float* __restrict__ Bt,
                                                 unsigned short* __restrict__ Wb,
                                                 int Din, int Dout) {
  __shared__ float sB[16 * RANK];
  int nib = Din / 256;
  int ib = blockIdx.x % nib;
  int ob = blockIdx.x / nib;
  int i0 = ib * 256, o0 = ob * 16;
  int t = threadIdx.x;

  if (t < 128) {
    reinterpret_cast<float4*>(sB)[t] =
        reinterpret_cast<const float4*>(Bt + (long long)o0 * RANK)[t];
  }

  float a[RANK];
  const float4* Ap = reinterpret_cast<const float4*>(A + (long long)(i0 + t) * RANK);
#pragma unroll
  for (int c = 0; c < RANK / 4; ++c) {
    float4 v = Ap[c];
    a[c * 4 + 0] = v.x; a[c * 4 + 1] = v.y;
    a[c * 4 + 2] = v.z; a[c * 4 + 3] = v.w;
  }
  __syncthreads();

  for (int o = 0; o < 16; ++o) {
    float d = 0.f;
#pragma unroll
    for (int j = 0; j < RANK; ++j) d += a[j] * sB[o * RANK + j];
    long long off = (long long)(o0 + o) * Din + i0 + t;
    float w = __builtin_nontemporal_load(&W[off]);
    Wb[off] = f2bf(w + SCALE * d);
  }
}

// ---------------------------------------------------------------------------
// x fp32 -> bf16, 8 elems/thread (nt loads via native ext_vector)
// ---------------------------------------------------------------------------
__global__ __launch_bounds__(256) void cast_x_k(const float* __restrict__ in,
                                                unsigned short* __restrict__ out,
                                                long long n8) {
  long long i = (long long)blockIdx.x * 256 + threadIdx.x;
  if (i >= n8) return;
  const f32x4* in4 = reinterpret_cast<const f32x4*>(in) + i * 2;
  f32x4 v0 = __builtin_nontemporal_load(in4);
  f32x4 v1 = __builtin_nontemporal_load(in4 + 1);
  union { unsigned short u[8]; uint4 q; } p;
  p.u[0] = f2bf(v0.x); p.u[1] = f2bf(v0.y); p.u[2] = f2bf(v0.z); p.u[3] = f2bf(v0.w);
  p.u[4] = f2bf(v1.x); p.u[5] = f2bf(v1.y); p.u[6] = f2bf(v1.z); p.u[7] = f2bf(v1.w);
  reinterpret_cast<uint4*>(out)[i] = p.q;
}

// ---------------------------------------------------------------------------
// R9 = R8 with the stage-koff bug fixed (R8 staged ko+96/ko+128 in the odd
// phases; correct is ko+64/ko+96 -> even tiles' A-hi was never staged).
//
// 256x256 / BK=32 / 8 waves (2Mx4N) / ONE barrier per phase /
// READ-AHEAD-1-PHASE register double-banking. 1 block/CU.
//
// Phase body = [vmcnt gate][barrier][stage][ds_reads for NEXT phase]
//              [sched_barrier(0)][setprio 16xMFMA]. Reads (<=8) drain under
// this phase's MFMA; MFMA operands were read LAST phase (compiler-counted
// lgkmcnt skips the new reads; DS returns in-order).
//
// Units (1 gload issue = 128 rows x 32k): lo(X)={Ra1,Rb1,Rb2}, Ra2(X).
// Tile X in buf[X&1].
// Stage map: PH1(X) stages Ra2(X+1)->buf[(X+1)&1] hi;
//            PH2(X) stages lo(X+2)->buf[X&1].
// Coverage: prologue lo(0),Ra2(0),lo(1); ph1_j Ra2(2j+1); ph2_j lo(2j+2);
// ph3_j Ra2(2j+2); ph4_j lo(2j+3); j=0..62; tail Ra2(127). Each unit once.
// Gates (in-order vmcnt): PH1(X): outstanding {Ra2(X), lo(X+1)} -> vmcnt(3)
// drains Ra2(X). PH2(X): outstanding {lo(X+1), Ra2(X+1)} -> vmcnt(1) drains
// lo(X+1). Tail: 3 -> 1 -> 0.
// WAR (all 4 phase positions checked): stage target's last ds_reads drain at
// the previous phase's counted-lgkm (before that phase's closing barrier);
// reads still outstanding at any barrier target regions disjoint from the
// post-barrier stage.
// Swizzle (64B rows = 4x16B chunks): chunk ^= (row ^ row>>2) & 3 on both
// sides (proven correct in R7).
// ---------------------------------------------------------------------------
__device__ __forceinline__ void stage1(const unsigned short* g, int K, int koff,
                                       int row0, unsigned short* ldsbase,
                                       int t, int wid) {
  int r = t >> 2;                               // 0..127 local row
  int cg = (t & 3) ^ ((r ^ (r >> 2)) & 3);      // inverse-swizzled 16B chunk
  gload16(g + (long long)(row0 + r) * K + koff + cg * 8,
          ldsbase + row0 * 32 + wid * 512);
}

__device__ __forceinline__ int swz_off32(int rowl, int k) {
  return rowl * 32 + ((((k) >> 3) ^ ((rowl ^ (rowl >> 2)) & 3)) << 3);
}

__global__ __launch_bounds__(512, 2) void gemm256_bias_k(
    const unsigned short* __restrict__ Xb,   // [M][K] bf16
    const unsigned short* __restrict__ Wb,   // [N][K] bf16
    const float* __restrict__ bias,          // [N]
    float* __restrict__ Out,                 // [M][N] fp32
    int M, int N, int K) {
  __shared__ unsigned short As[2][256 * 32];
  __shared__ unsigned short Bs[2][256 * 32];   // 64 KiB total

  int nbn = N / 256;
  int cpx = gridDim.x >> 3;
  int bid = blockIdx.x;
  int xcd = bid & 7, local = bid >> 3;
  int bm, bn;
  int mrows = cpx / nbn;
  if (mrows * nbn == cpx) {
    bn = local / mrows;
    bm = xcd * mrows + (local - bn * mrows);   // bm-fastest: B-panel L2-hot
  } else {
    int swz = xcd * cpx + local;
    bm = swz / nbn; bn = swz % nbn;
  }

  int t = threadIdx.x;
  int wid = t >> 6, lane = t & 63;
  int wr = wid >> 2, wc = wid & 3;             // 2x4 wave grid
  int lr = lane & 15, kq = (lane >> 4) * 8;
  int wr64 = wr * 64, wc32 = wc * 32;

  const unsigned short* ga = Xb + (long long)bm * 256 * K;
  const unsigned short* gb = Wb + (long long)bn * 256 * K;

  f32x4 acc[8][4] = {};
  bf16x8 aL0[4], aL1[4], aH0[4], aH1[4], bF0[4], bF1[4];

#define LDA(BUF, ROWBASE) \
  (*(const bf16x8*)&As[BUF][swz_off32((ROWBASE) + lr, kq)])
#define LDB(BUF, ROWBASE) \
  (*(const bf16x8*)&Bs[BUF][swz_off32((ROWBASE) + lr, kq)])

#define GATE(NSTR) \
  asm volatile("s_waitcnt vmcnt(" NSTR ")" ::: "memory"); \
  __builtin_amdgcn_s_barrier();

#define READ_AH(AH, BUF) \
  AH[0] = LDA(BUF, 128 + wr64);      AH[1] = LDA(BUF, 128 + wr64 + 16); \
  AH[2] = LDA(BUF, 128 + wr64 + 32); AH[3] = LDA(BUF, 128 + wr64 + 48);

#define READ_LOB(AL, BF, BUF) \
  AL[0] = LDA(BUF, wr64);      AL[1] = LDA(BUF, wr64 + 16); \
  AL[2] = LDA(BUF, wr64 + 32); AL[3] = LDA(BUF, wr64 + 48); \
  BF[0] = LDB(BUF, wc32);            BF[1] = LDB(BUF, wc32 + 16); \
  BF[2] = LDB(BUF, 128 + wc32);      BF[3] = LDB(BUF, 128 + wc32 + 16);

#define MFMA16(AF, BF, MO)                                                   \
  __builtin_amdgcn_sched_barrier(0);                                         \
  __builtin_amdgcn_s_setprio(1);                                             \
  _Pragma("unroll")                                                          \
  for (int m = 0; m < 4; ++m)                                                \
    _Pragma("unroll")                                                        \
    for (int n = 0; n < 4; ++n)                                              \
      acc[(MO) + m][n] = __builtin_amdgcn_mfma_f32_16x16x32_bf16(            \
          AF[m], BF[n], acc[(MO) + m][n], 0, 0, 0);                          \
  __builtin_amdgcn_s_setprio(0);

  // ---- prologue: lo(0), Ra2(0), lo(1); vmcnt(4) drains lo(0); read tile0 lo
  stage1(ga, K, 0, 0,    &As[0][0], t, wid);   // Ra1(0)
  stage1(gb, K, 0, 0,    &Bs[0][0], t, wid);   // Rb1(0)
  stage1(gb, K, 0, 128,  &Bs[0][0], t, wid);   // Rb2(0)
  stage1(ga, K, 0, 128,  &As[0][0], t, wid);   // Ra2(0)
  stage1(ga, K, 32, 0,   &As[1][0], t, wid);   // Ra1(1)
  stage1(gb, K, 32, 0,   &Bs[1][0], t, wid);   // Rb1(1)
  stage1(gb, K, 32, 128, &Bs[1][0], t, wid);   // Rb2(1)
  asm volatile("s_waitcnt vmcnt(4)" ::: "memory");
  __builtin_amdgcn_s_barrier();
  READ_LOB(aL0, bF0, 0)

  // ---- steady loop: iter j covers X=2j (bank0) and X=2j+1 (bank1);
  // stages: ph1 Ra2(2j+1)@ko+32->As[1], ph2 lo(2j+2)@ko+64->buf0,
  //         ph3 Ra2(2j+2)@ko+64->As[0], ph4 lo(2j+3)@ko+96->buf1.
  // j=0..62: max koff = 64*62+96 = 4064 = 127*32, in range.
  for (int j = 0; j < 63; ++j) {
    int ko = j * 64;  // = 2j*32
    // PH1(X=2j): stage Ra2(X+1)->As[1]hi; read aH0; MFMA lo
    GATE("3")
    stage1(ga, K, ko + 32, 128, &As[1][0], t, wid);
    READ_AH(aH0, 0)
    MFMA16(aL0, bF0, 0)
    // PH2(X=2j): stage lo(X+2)->buf0; read aL1,bF1 (tile X+1); MFMA hi
    GATE("1")
    stage1(ga, K, ko + 64, 0,   &As[0][0], t, wid);
    stage1(gb, K, ko + 64, 0,   &Bs[0][0], t, wid);
    stage1(gb, K, ko + 64, 128, &Bs[0][0], t, wid);
    READ_LOB(aL1, bF1, 1)
    MFMA16(aH0, bF0, 4)
    // PH1(X=2j+1): stage Ra2(X+1=2j+2)->As[0]hi; read aH1; MFMA lo
    GATE("3")
    stage1(ga, K, ko + 64, 128, &As[0][0], t, wid);
    READ_AH(aH1, 1)
    MFMA16(aL1, bF1, 0)
    // PH2(X=2j+1): stage lo(X+2=2j+3)->buf1; read aL0,bF0 (tile X+2); MFMA hi
    GATE("1")
    stage1(ga, K, ko + 96, 0,   &As[1][0], t, wid);
    stage1(gb, K, ko + 96, 0,   &Bs[1][0], t, wid);
    stage1(gb, K, ko + 96, 128, &Bs[1][0], t, wid);
    READ_LOB(aL0, bF0, 0)
    MFMA16(aH1, bF1, 4)
  }

  // ---- peeled tail: X=126 (bank0), X=127 (bank1)
  // PH1(126): needs Ra2(126) [staged ph3 j=62]; outstanding lo(127)[3]
  GATE("3")
  stage1(ga, K, 127 * 32, 128, &As[1][0], t, wid);   // Ra2(127)->buf1 hi
  READ_AH(aH0, 0)
  MFMA16(aL0, bF0, 0)
  // PH2(126): needs lo(127); outstanding {lo(127)[3], Ra2(127)[1]} -> vmcnt(1)
  GATE("1")
  READ_LOB(aL1, bF1, 1)
  MFMA16(aH0, bF0, 4)
  // PH1(127): needs Ra2(127) -> drain all
  GATE("0")
  READ_AH(aH1, 1)
  MFMA16(aL1, bF1, 0)
  // PH2(127): regs only
  MFMA16(aH1, bF1, 4)

#undef LDA
#undef LDB
#undef GATE
#undef READ_AH
#undef READ_LOB
#undef MFMA16

  // epilogue (nt stores), same output map as R4/R6:
  // rows: m<4 -> wr64 + m*16 ; m>=4 -> 128 + wr64 + (m-4)*16
  // cols: n<2 -> wc32 + n*16 ; n>=2 -> 128 + wc32 + (n-2)*16
  int rq = (lane >> 4) * 4;
#pragma unroll
  for (int n = 0; n < 4; ++n) {
    int gc = bn * 256 + (n >= 2 ? 128 : 0) + wc32 + (n & 1) * 16 + lr;
    float bv = bias[gc];
#pragma unroll
    for (int m = 0; m < 8; ++m) {
      long long gr = (long long)bm * 256 + (m >= 4 ? 128 : 0) + wr64 + (m & 3) * 16 + rq;
#pragma unroll
      for (int v = 0; v < 4; ++v)
        __builtin_nontemporal_store(acc[m][n][v] + bv, &Out[(gr + v) * N + gc]);
    }
  }
}

// ---------------------------------------------------------------------------
extern "C" void kernel_launch(void* const* d_in, const int* in_sizes, int n_in,
                              void* d_out, int out_size, void* d_ws, size_t ws_size,
                              hipStream_t stream) {
  const float* x    = (const float*)d_in[0];
  const float* W    = (const float*)d_in[1];
  const float* bias = (const float*)d_in[2];
  const float* A    = (const float*)d_in[3];
  const float* B    = (const float*)d_in[4];

  int Din  = in_sizes[3] / RANK;                 // 4096
  int Dout = in_sizes[4] / RANK;                 // 4096
  long long M = (long long)in_sizes[0] / Din;    // 8192

  size_t xb_bytes = (size_t)M * Din * 2;
  size_t wb_bytes = (size_t)Dout * Din * 2;
  size_t bt_bytes = (size_t)Dout * RANK * 4;
  if (ws_size < xb_bytes + wb_bytes + bt_bytes) return;

  char* ws = (char*)d_ws;
  unsigned short* Xb = (unsigned short*)ws;
  unsigned short* Wb = (unsigned short*)(ws + xb_bytes);
  float* Bt          = (float*)(ws + xb_bytes + wb_bytes);

  transpose_B_k<<<dim3((Dout * RANK) / 256), dim3(256), 0, stream>>>(B, Bt, Dout);
  merge_W_k<<<dim3((Dout / 16) * (Din / 256)), dim3(256), 0, stream>>>(W, A, Bt, Wb, Din, Dout);
  long long n8 = M * Din / 8;
  cast_x_k<<<dim3((unsigned)(n8 / 256)), dim3(256), 0, stream>>>(x, Xb, n8);
  gemm256_bias_k<<<dim3((unsigned)((M / 256) * (Dout / 256))), dim3(512), 0, stream>>>(
      Xb, Wb, bias, (float*)d_out, (int)M, Dout, Din);
}

// Round 10
// 329.474 us; speedup vs baseline: 6.3444x; 1.0495x over previous
//
#include <hip/hip_runtime.h>
#include <hip/hip_bf16.h>
#include <stdint.h>

#define RANK 32
#define SCALE (1.0f / 32.0f)

typedef __bf16 bf16x8 __attribute__((ext_vector_type(8)));
typedef float f32x4 __attribute__((ext_vector_type(4)));

// ---------------------------------------------------------------------------
// async global->LDS, 16B per lane
// ---------------------------------------------------------------------------
__device__ __forceinline__ void gload16(const void* g, void* l) {
  __builtin_amdgcn_global_load_lds(
      (const __attribute__((address_space(1))) unsigned int*)g,
      (__attribute__((address_space(3))) unsigned int*)l, 16, 0, 0);
}

__device__ __forceinline__ unsigned short f2bf(float f) {
  __hip_bfloat16 h = __float2bfloat16(f);
  return *reinterpret_cast<unsigned short*>(&h);
}

// ---------------------------------------------------------------------------
// Bt[o][r] = B[r][o]
// ---------------------------------------------------------------------------
__global__ __launch_bounds__(256) void transpose_B_k(const float* __restrict__ B,
                                                     float* __restrict__ Bt,
                                                     int Dout) {
  int idx = blockIdx.x * 256 + threadIdx.x;
  int r = idx / Dout;
  int o = idx - r * Dout;
  Bt[(long long)o * RANK + r] = B[idx];
}

// ---------------------------------------------------------------------------
// W' = W + SCALE * (A@B)^T, cast bf16, stored PRE-FRAGMENTED for the GEMM:
//   Wbf[nb][kb][slot][e] ; nb=o>>4, kb=i>>5, slot=((i&31)>>3)*16+(o&15), e=i&7
// A wave's B-fragment (nb, kb) is then a contiguous 1KB block where lane l
// reads 16B at +l*16: exactly the mfma_16x16x32 B operand layout
// (l&15 = col within 16, l>>4 = k-quarter).
// ---------------------------------------------------------------------------
__global__ __launch_bounds__(256) void merge_W_k(const float* __restrict__ W,
                                                 const float* __restrict__ A,
                                                 const float* __restrict__ Bt,
                                                 unsigned short* __restrict__ Wbf,
                                                 int Din, int Dout) {
  __shared__ float sB[16 * RANK];
  int nib = Din / 256;
  int ib = blockIdx.x % nib;
  int ob = blockIdx.x / nib;
  int i0 = ib * 256, o0 = ob * 16;
  int t = threadIdx.x;

  if (t < 128) {
    reinterpret_cast<float4*>(sB)[t] =
        reinterpret_cast<const float4*>(Bt + (long long)o0 * RANK)[t];
  }

  float a[RANK];
  const float4* Ap = reinterpret_cast<const float4*>(A + (long long)(i0 + t) * RANK);
#pragma unroll
  for (int c = 0; c < RANK / 4; ++c) {
    float4 v = Ap[c];
    a[c * 4 + 0] = v.x; a[c * 4 + 1] = v.y;
    a[c * 4 + 2] = v.z; a[c * 4 + 3] = v.w;
  }
  __syncthreads();

  int i = i0 + t;
  int KB = Din / 32;
  long long fragrow = (long long)(o0 >> 4) * KB + (i >> 5);  // nb*KB + kb
  int slot_base = ((i & 31) >> 3) * 16;                       // + o
  int e = i & 7;

  for (int o = 0; o < 16; ++o) {
    float d = 0.f;
#pragma unroll
    for (int j = 0; j < RANK; ++j) d += a[j] * sB[o * RANK + j];
    long long off = (long long)(o0 + o) * Din + i;
    float w = __builtin_nontemporal_load(&W[off]);
    Wbf[fragrow * 512 + (slot_base + o) * 8 + e] = f2bf(w + SCALE * d);
  }
}

// ---------------------------------------------------------------------------
// x fp32 -> bf16, 8 elems/thread (nt loads via native ext_vector)
// ---------------------------------------------------------------------------
__global__ __launch_bounds__(256) void cast_x_k(const float* __restrict__ in,
                                                unsigned short* __restrict__ out,
                                                long long n8) {
  long long i = (long long)blockIdx.x * 256 + threadIdx.x;
  if (i >= n8) return;
  const f32x4* in4 = reinterpret_cast<const f32x4*>(in) + i * 2;
  f32x4 v0 = __builtin_nontemporal_load(in4);
  f32x4 v1 = __builtin_nontemporal_load(in4 + 1);
  union { unsigned short u[8]; uint4 q; } p;
  p.u[0] = f2bf(v0.x); p.u[1] = f2bf(v0.y); p.u[2] = f2bf(v0.z); p.u[3] = f2bf(v0.w);
  p.u[4] = f2bf(v1.x); p.u[5] = f2bf(v1.y); p.u[6] = f2bf(v1.z); p.u[7] = f2bf(v1.w);
  reinterpret_cast<uint4*>(out)[i] = p.q;
}

// ---------------------------------------------------------------------------
// R10: 256x256 / BK=32 / 8 waves (2Mx4N) / A-only LDS (32KB dbuf) /
// B DIRECT FROM GLOBAL (fragged Wbf layout, L2-hot) — removes 33% of the
// per-CU LDS read pipe (96->64KB per K32) and all B staging.
//
// Sets per phase (vmcnt items; sets fenced by asm memory-clobber gates):
//   PH1(X): stage Ra2(X+1)->As[(X+1)&1]hi [1] ; load Bv(X+1)->other bank [4]
//   PH2(X): stage Ra1(X+2)->As[X&1]lo [1]
// Gates (in-order vmcnt):
//   PH1(X): needs {Ra2(X),Bv(X)}; newer = {Ra1(X+1)} -> vmcnt(1)
//   PH2(X): needs {Ra1(X+1)}; newer = {Ra2(X+1),Bv(X+1)} -> vmcnt(5)
//   Tail: PH1(127) vmcnt(0).
// Reads: PH1 reads aH(X) [4 ds]; PH2 reads aL(X+1) [4 ds]; MFMA operands
// always read/loaded >=1 phase before use (compiler-counted waits).
// WAR: Ra2(X+1) overwrites As hi last ds-read at PH1(X-1) (2 phases back);
// Ra1(X+2) overwrites As lo last ds-read at PH2(X-1) (1 phase + barrier).
// Swizzle: chunk ^= (row ^ row>>2)&3 both sides (proven R7/R9).
// ---------------------------------------------------------------------------
__device__ __forceinline__ void stage1(const unsigned short* g, int K, int koff,
                                       int row0, unsigned short* ldsbase,
                                       int t, int wid) {
  int r = t >> 2;                               // 0..127 local row
  int cg = (t & 3) ^ ((r ^ (r >> 2)) & 3);      // inverse-swizzled 16B chunk
  gload16(g + (long long)(row0 + r) * K + koff + cg * 8,
          ldsbase + row0 * 32 + wid * 512);
}

__device__ __forceinline__ int swz_off32(int rowl, int k) {
  return rowl * 32 + ((((k) >> 3) ^ ((rowl ^ (rowl >> 2)) & 3)) << 3);
}

__global__ __launch_bounds__(512, 2) void gemm256_bias_k(
    const unsigned short* __restrict__ Xb,    // [M][K] bf16
    const unsigned short* __restrict__ Wbf,   // fragged [N/16][K/32][64][8]
    const float* __restrict__ bias,           // [N]
    float* __restrict__ Out,                  // [M][N] fp32
    int M, int N, int K) {
  __shared__ unsigned short As[2][256 * 32];  // 32 KiB

  int nbn = N / 256;
  int cpx = gridDim.x >> 3;
  int bid = blockIdx.x;
  int xcd = bid & 7, local = bid >> 3;
  int bm, bn;
  int mrows = cpx / nbn;
  if (mrows * nbn == cpx) {
    bn = local / mrows;
    bm = xcd * mrows + (local - bn * mrows);   // bm-fastest: B-panel L2-hot
  } else {
    int swz = xcd * cpx + local;
    bm = swz / nbn; bn = swz % nbn;
  }

  int t = threadIdx.x;
  int wid = t >> 6, lane = t & 63;
  int wr = wid >> 2, wc = wid & 3;             // 2x4 wave grid
  int lr = lane & 15, kq = (lane >> 4) * 8;
  int wr64 = wr * 64, wc32 = wc * 32;

  const unsigned short* ga = Xb + (long long)bm * 256 * K;
  const int KB = K / 32;                        // 128
  // B frag row bases: nb0 = bn*16 + wc*2; frags at nb0 + {0,1,8,9}
  const unsigned short* gbf = Wbf + ((long long)(bn * 16 + wc * 2) * KB) * 512
                                  + lane * 8;

  f32x4 acc[8][4] = {};
  bf16x8 aL0[4], aL1[4], aH0[4], aH1[4], Bv0[4], Bv1[4];

#define LDA(BUF, ROWBASE) \
  (*(const bf16x8*)&As[BUF][swz_off32((ROWBASE) + lr, kq)])

#define GATE(NSTR) \
  asm volatile("s_waitcnt vmcnt(" NSTR ")" ::: "memory"); \
  __builtin_amdgcn_s_barrier();

#define READ_AH(AH, BUF) \
  AH[0] = LDA(BUF, 128 + wr64);      AH[1] = LDA(BUF, 128 + wr64 + 16); \
  AH[2] = LDA(BUF, 128 + wr64 + 32); AH[3] = LDA(BUF, 128 + wr64 + 48);

#define READ_AL(AL, BUF) \
  AL[0] = LDA(BUF, wr64);      AL[1] = LDA(BUF, wr64 + 16); \
  AL[2] = LDA(BUF, wr64 + 32); AL[3] = LDA(BUF, wr64 + 48);

#define LOADB(BV, T) { \
  const unsigned short* fb = gbf + (long long)(T) * 512;               \
  BV[0] = *(const bf16x8*)(fb);                                        \
  BV[1] = *(const bf16x8*)(fb + (long long)KB * 512);                  \
  BV[2] = *(const bf16x8*)(fb + (long long)8 * KB * 512);              \
  BV[3] = *(const bf16x8*)(fb + (long long)9 * KB * 512); }

#define MFMA16(AF, BF, MO)                                                   \
  __builtin_amdgcn_sched_barrier(0);                                         \
  __builtin_amdgcn_s_setprio(1);                                             \
  _Pragma("unroll")                                                          \
  for (int m = 0; m < 4; ++m)                                                \
    _Pragma("unroll")                                                        \
    for (int n = 0; n < 4; ++n)                                              \
      acc[(MO) + m][n] = __builtin_amdgcn_mfma_f32_16x16x32_bf16(            \
          AF[m], BF[n], acc[(MO) + m][n], 0, 0, 0);                          \
  __builtin_amdgcn_s_setprio(0);

  // ---- prologue: Ra1(0), Ra2(0), Bv(0), Ra1(1); vmcnt(1) leaves Ra1(1)
  stage1(ga, K, 0, 0,    &As[0][0], t, wid);   // Ra1(0)
  stage1(ga, K, 0, 128,  &As[0][0], t, wid);   // Ra2(0)
  LOADB(Bv0, 0)                                 // Bv(0) [4]
  stage1(ga, K, 32, 0,   &As[1][0], t, wid);   // Ra1(1)
  asm volatile("s_waitcnt vmcnt(1)" ::: "memory");
  __builtin_amdgcn_s_barrier();
  READ_AL(aL0, 0)

  // ---- steady loop: j covers X=2j (bank0/As[0]) and X=2j+1 (bank1/As[1]);
  // j=0..62 -> X<=125; all staged indices <=127.
  for (int j = 0; j < 63; ++j) {
    int ko = j * 64;  // 2j*32
    // PH1(X=2j): stage Ra2(X+1); load Bv(X+1); read aH(X); MFMA lo
    GATE("1")
    stage1(ga, K, ko + 32, 128, &As[1][0], t, wid);
    LOADB(Bv1, 2 * j + 1)
    READ_AH(aH0, 0)
    MFMA16(aL0, Bv0, 0)
    // PH2(X=2j): stage Ra1(X+2); read aL(X+1); MFMA hi
    GATE("5")
    stage1(ga, K, ko + 64, 0, &As[0][0], t, wid);
    READ_AL(aL1, 1)
    MFMA16(aH0, Bv0, 4)
    // PH1(X=2j+1): stage Ra2(X+2); load Bv(X+2); read aH(X+1); MFMA lo
    GATE("1")
    stage1(ga, K, ko + 64, 128, &As[0][0], t, wid);
    LOADB(Bv0, 2 * j + 2)
    READ_AH(aH1, 1)
    MFMA16(aL1, Bv1, 0)
    // PH2(X=2j+1): stage Ra1(X+3); read aL(X+2); MFMA hi
    GATE("5")
    stage1(ga, K, ko + 96, 0, &As[1][0], t, wid);
    READ_AL(aL0, 0)
    MFMA16(aH1, Bv1, 4)
  }

  // ---- peeled tail: X=126 (bank0), X=127 (bank1)
  // PH1(126): outstanding {Ra2(126),Bv(126),Ra1(127)} -> vmcnt(1)
  GATE("1")
  stage1(ga, K, 127 * 32, 128, &As[1][0], t, wid);   // Ra2(127)
  LOADB(Bv1, 127)                                     // Bv(127)
  READ_AH(aH0, 0)
  MFMA16(aL0, Bv0, 0)
  // PH2(126): outstanding {Ra1(127),Ra2(127),Bv(127)}=6 -> vmcnt(5)
  GATE("5")
  READ_AL(aL1, 1)
  MFMA16(aH0, Bv0, 4)
  // PH1(127): needs Ra2(127)+Bv(127) -> vmcnt(0)
  GATE("0")
  READ_AH(aH1, 1)
  MFMA16(aL1, Bv1, 0)
  // PH2(127): regs only
  MFMA16(aH1, Bv1, 4)

#undef LDA
#undef GATE
#undef READ_AH
#undef READ_AL
#undef LOADB
#undef MFMA16

  // epilogue (nt stores), same output map as R4/R6/R9:
  // rows: m<4 -> wr64 + m*16 ; m>=4 -> 128 + wr64 + (m-4)*16
  // cols: n<2 -> wc32 + n*16 ; n>=2 -> 128 + wc32 + (n-2)*16
  int rq = (lane >> 4) * 4;
#pragma unroll
  for (int n = 0; n < 4; ++n) {
    int gc = bn * 256 + (n >= 2 ? 128 : 0) + wc32 + (n & 1) * 16 + lr;
    float bv = bias[gc];
#pragma unroll
    for (int m = 0; m < 8; ++m) {
      long long gr = (long long)bm * 256 + (m >= 4 ? 128 : 0) + wr64 + (m & 3) * 16 + rq;
#pragma unroll
      for (int v = 0; v < 4; ++v)
        __builtin_nontemporal_store(acc[m][n][v] + bv, &Out[(gr + v) * N + gc]);
    }
  }
}

// ---------------------------------------------------------------------------
extern "C" void kernel_launch(void* const* d_in, const int* in_sizes, int n_in,
                              void* d_out, int out_size, void* d_ws, size_t ws_size,
                              hipStream_t stream) {
  const float* x    = (const float*)d_in[0];
  const float* W    = (const float*)d_in[1];
  const float* bias = (const float*)d_in[2];
  const float* A    = (const float*)d_in[3];
  const float* B    = (const float*)d_in[4];

  int Din  = in_sizes[3] / RANK;                 // 4096
  int Dout = in_sizes[4] / RANK;                 // 4096
  long long M = (long long)in_sizes[0] / Din;    // 8192

  size_t xb_bytes = (size_t)M * Din * 2;
  size_t wb_bytes = (size_t)Dout * Din * 2;
  size_t bt_bytes = (size_t)Dout * RANK * 4;
  if (ws_size < xb_bytes + wb_bytes + bt_bytes) return;

  char* ws = (char*)d_ws;
  unsigned short* Xb  = (unsigned short*)ws;
  unsigned short* Wbf = (unsigned short*)(ws + xb_bytes);
  float* Bt           = (float*)(ws + xb_bytes + wb_bytes);

  transpose_B_k<<<dim3((Dout * RANK) / 256), dim3(256), 0, stream>>>(B, Bt, Dout);
  merge_W_k<<<dim3((Dout / 16) * (Din / 256)), dim3(256), 0, stream>>>(W, A, Bt, Wbf, Din, Dout);
  long long n8 = M * Din / 8;
  cast_x_k<<<dim3((unsigned)(n8 / 256)), dim3(256), 0, stream>>>(x, Xb, n8);
  gemm256_bias_k<<<dim3((unsigned)((M / 256) * (Dout / 256))), dim3(512), 0, stream>>>(
      Xb, Wbf, bias, (float*)d_out, (int)M, Dout, Din);
}